// Round 4
// baseline (2293.456 us; speedup 1.0000x reference)
//
#include <hip/hip_runtime.h>
#include <hip/hip_bf16.h>

#define TPB  512
#define NBLK 256

typedef short    short8 __attribute__((ext_vector_type(8)));
typedef float    f32x4  __attribute__((ext_vector_type(4)));
typedef unsigned uint4v __attribute__((ext_vector_type(4)));

#define PROW 136            // panel row stride in shorts (272B = odd*16B)
#define PSZ  (128 * PROW)   // shorts per panel

__device__ __forceinline__ float fast_tanh(float z) {
    float e = __expf(2.0f * z);
    return 1.0f - 2.0f * __builtin_amdgcn_rcpf(e + 1.0f);
}

__device__ __forceinline__ unsigned short bf16_bits(float v) {
    __hip_bfloat16 b = __float2bfloat16(v);
    unsigned short s; __builtin_memcpy(&s, &b, 2);
    return s;
}

__device__ __forceinline__ unsigned pack_bf2(float lo, float hi) {
    return (unsigned)bf16_bits(lo) | ((unsigned)bf16_bits(hi) << 16);
}

// B-frag kk = bf16 pack of acc rows (nt=kk, nt=kk+4)  [sigma k-permutation]
__device__ __forceinline__ short8 packB(f32x4 lo, f32x4 hi) {
    uint4v u;
    u[0] = pack_bf2(lo[0], lo[1]);
    u[1] = pack_bf2(lo[2], lo[3]);
    u[2] = pack_bf2(hi[0], hi[1]);
    u[3] = pack_bf2(hi[2], hi[3]);
    return __builtin_bit_cast(short8, u);
}

// read back acc-position (nt,q) from packed B-frags (nt,q compile-time)
__device__ __forceinline__ float unpB(const short8* B, int nt, int q) {
    unsigned short us = B[nt & 3][((nt >> 2) << 2) | q];
    return __builtin_bit_cast(float, ((unsigned)us) << 16);
}

// One GEMM D[n][s] += A(panel)*B, single B-stream, acc 8x f32x4 (32 VGPR).
__device__ __forceinline__ void gemm1(const unsigned short* __restrict__ pnl,
                                      int c, int g, const short8 B[4], f32x4 acc[8]) {
    #pragma unroll
    for (int kk = 0; kk < 4; kk++) {
        #pragma unroll
        for (int nt = 0; nt < 8; nt++) {
            const short8 af = *reinterpret_cast<const short8*>(
                pnl + (nt * 16 + c) * PROW + kk * 32 + g * 8);
            acc[nt] = __builtin_amdgcn_mfma_f32_16x16x32_bf16(af, B[kk], acc[nt], 0, 0, 0);
        }
    }
}

__device__ __forceinline__ void zero_acc(f32x4 acc[8]) {
    #pragma unroll
    for (int nt = 0; nt < 8; nt++) acc[nt] = f32x4{0.f, 0.f, 0.f, 0.f};
}

__global__ __launch_bounds__(TPB, 2) __attribute__((amdgpu_waves_per_eu(2, 2)))
void mlp_mfma_kernel(
    const float* __restrict__ X,
    const float* __restrict__ gW1, const float* __restrict__ gB1,
    const float* __restrict__ gW2, const float* __restrict__ gB2,
    const float* __restrict__ gW3, const float* __restrict__ gB3,
    const float* __restrict__ gW4, const float* __restrict__ gB4,
    float* __restrict__ out, int N)
{
    // 4 weight panels as MFMA A-operands: [n][sigma(k)], row stride 136 shorts.
    // 0: W2 fwd (W2[f][n])  1: W2 bwd (W2[n][f])  2: W3 fwd  3: W3 bwd
    __shared__ alignas(16) unsigned short sPanel[4 * PSZ];      // 139264 B
    __shared__ alignas(16) float sParam[7 * 128];               // w1t w1x w1y b1 b2 b3 w4

    const int tid = threadIdx.x;
    for (int idx = tid; idx < 4 * 128 * 128; idx += TPB) {
        int p = idx >> 14, e = idx & 16383, n = e >> 7, pp = e & 127;
        int kk = pp >> 5, gg = (pp >> 3) & 3, jj = pp & 7;
        int f = ((((jj >> 2) << 2) | kk) << 4) | (gg << 2) | (jj & 3);  // invsigma
        const float* Wsrc = (p < 2) ? gW2 : gW3;
        float v = (p & 1) ? Wsrc[n * 128 + f] : Wsrc[f * 128 + n];
        sPanel[p * PSZ + n * PROW + pp] = bf16_bits(v);
    }
    if (tid < 128) {
        sParam[0 * 128 + tid] = gW1[tid];
        sParam[1 * 128 + tid] = gW1[128 + tid];
        sParam[2 * 128 + tid] = gW1[256 + tid];
        sParam[3 * 128 + tid] = gB1[tid];
        sParam[4 * 128 + tid] = gB2[tid];
        sParam[5 * 128 + tid] = gB3[tid];
        sParam[6 * 128 + tid] = gW4[tid];
    }
    __syncthreads();

    const int lane = tid & 63;
    const int wave = tid >> 6;
    const int c = lane & 15, g = lane >> 4;
    const int fb = g << 2;   // lane's feature offset within each 16-row tile
    const unsigned short* const pW2f = sPanel;
    const unsigned short* const pW2b = sPanel + PSZ;
    const unsigned short* const pW3f = sPanel + 2 * PSZ;
    const unsigned short* const pW3b = sPanel + 3 * PSZ;
    const float b4 = gB4[0];

    const int tiles = N >> 4;
    for (int t = blockIdx.x * 8 + wave; t < tiles; t += NBLK * 8) {
        const int sbase = t << 4;
        const float* xp = X + (long)(sbase + c) * 3;
        const float xt = xp[0], xx = xp[1], xy = xp[2];

        // ---- Phase A: h1 = tanh(x @ W1 + b1), packed only ----
        short8 h1B[4];
        #pragma unroll
        for (int kk = 0; kk < 4; kk++) {
            f32x4 lo, hi;
            #pragma unroll
            for (int half = 0; half < 2; half++) {
                const int nt = kk + half * 4, f0 = nt * 16 + fb;
                f32x4 wt = *(const f32x4*)(sParam + 0 * 128 + f0);
                f32x4 wx = *(const f32x4*)(sParam + 1 * 128 + f0);
                f32x4 wy = *(const f32x4*)(sParam + 2 * 128 + f0);
                f32x4 bb = *(const f32x4*)(sParam + 3 * 128 + f0);
                f32x4 r;
                #pragma unroll
                for (int q = 0; q < 4; q++)
                    r[q] = fast_tanh(fmaf(xt, wt[q], fmaf(xx, wx[q], fmaf(xy, wy[q], bb[q]))));
                if (half) hi = r; else lo = r;
            }
            h1B[kk] = packB(lo, hi);
        }

        f32x4 acc[8];
        // ---- z2 = W2^T h1 + b2 ----
        #pragma unroll
        for (int nt = 0; nt < 8; nt++)
            acc[nt] = *(const f32x4*)(sParam + 4 * 128 + nt * 16 + fb);
        gemm1(pW2f, c, g, h1B, acc);

        // ---- h2 ----
        short8 h2B[4];
        #pragma unroll
        for (int kk = 0; kk < 4; kk++) {
            f32x4 lo, hi;
            #pragma unroll
            for (int q = 0; q < 4; q++) {
                lo[q] = fast_tanh(acc[kk][q]);
                hi[q] = fast_tanh(acc[kk + 4][q]);
            }
            h2B[kk] = packB(lo, hi);
        }

        // ---- z3 = W3^T h2 + b3 ----
        #pragma unroll
        for (int nt = 0; nt < 8; nt++)
            acc[nt] = *(const f32x4*)(sParam + 5 * 128 + nt * 16 + fb);
        gemm1(pW3f, c, g, h2B, acc);

        // ---- h3, value out, d3 ----
        short8 h3B[4], d3B[4];
        {
            float cp = 0.f;
            #pragma unroll
            for (int kk = 0; kk < 4; kk++) {
                f32x4 hlo, hhi, dlo, dhi;
                #pragma unroll
                for (int half = 0; half < 2; half++) {
                    const int nt = kk + half * 4;
                    f32x4 w4v = *(const f32x4*)(sParam + 6 * 128 + nt * 16 + fb);
                    #pragma unroll
                    for (int q = 0; q < 4; q++) {
                        float h = fast_tanh(acc[nt][q]);
                        float a = 1.f - h * h;
                        cp = fmaf(h, w4v[q], cp);
                        if (half) { hhi[q] = h; dhi[q] = w4v[q] * a; }
                        else      { hlo[q] = h; dlo[q] = w4v[q] * a; }
                    }
                }
                h3B[kk] = packB(hlo, hhi);
                d3B[kk] = packB(dlo, dhi);
            }
            cp += __shfl_xor(cp, 16, 64);
            cp += __shfl_xor(cp, 32, 64);
            if (lane < 16) out[sbase + lane] = cp + b4;
        }

        // ---- u2 = W3 d3 ----
        zero_acc(acc);
        gemm1(pW3b, c, g, d3B, acc);
        short8 u2B[4], d2B[4];
        #pragma unroll
        for (int kk = 0; kk < 4; kk++) {
            u2B[kk] = packB(acc[kk], acc[kk + 4]);
            f32x4 lo, hi;
            #pragma unroll
            for (int q = 0; q < 4; q++) {
                float h2l = unpB(h2B, kk, q),     h2h = unpB(h2B, kk + 4, q);
                lo[q] = acc[kk][q]     * (1.f - h2l * h2l);
                hi[q] = acc[kk + 4][q] * (1.f - h2h * h2h);
            }
            d2B[kk] = packB(lo, hi);
        }

        // ---- u1 = W2 d2 ----
        zero_acc(acc);
        gemm1(pW2b, c, g, d2B, acc);

        // ---- gradients (u1 still f32 in acc) + save u1B ----
        short8 u1B[4];
        {
            float gt = 0.f, gx = 0.f, gy = 0.f;
            #pragma unroll
            for (int nt = 0; nt < 8; nt++) {
                const int f0 = nt * 16 + fb;
                f32x4 wt = *(const f32x4*)(sParam + 0 * 128 + f0);
                f32x4 wx = *(const f32x4*)(sParam + 1 * 128 + f0);
                f32x4 wy = *(const f32x4*)(sParam + 2 * 128 + f0);
                #pragma unroll
                for (int q = 0; q < 4; q++) {
                    float h = unpB(h1B, nt, q);
                    float d1 = acc[nt][q] * (1.f - h * h);
                    gt = fmaf(d1, wt[q], gt);
                    gx = fmaf(d1, wx[q], gx);
                    gy = fmaf(d1, wy[q], gy);
                }
            }
            gt += __shfl_xor(gt, 16, 64); gt += __shfl_xor(gt, 32, 64);
            gx += __shfl_xor(gx, 16, 64); gx += __shfl_xor(gx, 32, 64);
            gy += __shfl_xor(gy, 16, 64); gy += __shfl_xor(gy, 32, 64);
            if (lane < 16) {
                long s = sbase + lane;
                out[(long)N + s] = gt;
                out[2L * N + s]  = gx;
                out[3L * N + s]  = gy;
            }
            #pragma unroll
            for (int kk = 0; kk < 4; kk++) u1B[kk] = packB(acc[kk], acc[kk + 4]);
        }

        // ---- HVP passes (dir 0: e_x -> W1 row 1; dir 1: e_y -> W1 row 2) ----
        for (int dir = 0; dir < 2; dir++) {
            const float* wr = sParam + (dir ? 2 : 1) * 128;

            // th1 = (1 - h1^2) * w1r
            short8 t1B[4];
            #pragma unroll
            for (int kk = 0; kk < 4; kk++) {
                f32x4 lo, hi;
                #pragma unroll
                for (int half = 0; half < 2; half++) {
                    const int nt = kk + half * 4;
                    f32x4 wrv = *(const f32x4*)(wr + nt * 16 + fb);
                    f32x4 r;
                    #pragma unroll
                    for (int q = 0; q < 4; q++) {
                        float h = unpB(h1B, nt, q);
                        r[q] = (1.f - h * h) * wrv[q];
                    }
                    if (half) hi = r; else lo = r;
                }
                t1B[kk] = packB(lo, hi);
            }

            zero_acc(acc);
            gemm1(pW2f, c, g, t1B, acc);     // tz2

            // th2 = (1 - h2^2) * tz2
            short8 t2B[4];
            #pragma unroll
            for (int kk = 0; kk < 4; kk++) {
                f32x4 lo, hi;
                #pragma unroll
                for (int q = 0; q < 4; q++) {
                    float h2l = unpB(h2B, kk, q),     h2h = unpB(h2B, kk + 4, q);
                    lo[q] = (1.f - h2l * h2l) * acc[kk][q];
                    hi[q] = (1.f - h2h * h2h) * acc[kk + 4][q];
                }
                t2B[kk] = packB(lo, hi);
            }

            zero_acc(acc);
            gemm1(pW3f, c, g, t2B, acc);     // tz3

            // td3 = -2 w4 h3 th3,  th3 = (1 - h3^2) * tz3
            short8 td3B[4];
            #pragma unroll
            for (int kk = 0; kk < 4; kk++) {
                f32x4 lo, hi;
                #pragma unroll
                for (int half = 0; half < 2; half++) {
                    const int nt = kk + half * 4;
                    f32x4 w4v = *(const f32x4*)(sParam + 6 * 128 + nt * 16 + fb);
                    f32x4 r;
                    #pragma unroll
                    for (int q = 0; q < 4; q++) {
                        float h = unpB(h3B, nt, q);
                        float th3 = (1.f - h * h) * acc[nt][q];
                        r[q] = -2.f * w4v[q] * h * th3;
                    }
                    if (half) hi = r; else lo = r;
                }
                td3B[kk] = packB(lo, hi);
            }

            zero_acc(acc);
            gemm1(pW3b, c, g, td3B, acc);    // tu2

            // td2 = tu2*(1-h2^2) - 2 u2 h2 th2
            short8 td2B[4];
            #pragma unroll
            for (int kk = 0; kk < 4; kk++) {
                f32x4 lo, hi;
                #pragma unroll
                for (int half = 0; half < 2; half++) {
                    const int nt = kk + half * 4;
                    f32x4 r;
                    #pragma unroll
                    for (int q = 0; q < 4; q++) {
                        float h   = unpB(h2B, nt, q);
                        float th2 = unpB(t2B, nt, q);
                        float u2  = unpB(u2B, nt, q);
                        r[q] = acc[nt][q] * (1.f - h * h) - 2.f * u2 * h * th2;
                    }
                    if (half) hi = r; else lo = r;
                }
                td2B[kk] = packB(lo, hi);
            }

            zero_acc(acc);
            gemm1(pW2b, c, g, td2B, acc);    // tu1

            // hv = sum td1 * w1r,  td1 = tu1*(1-h1^2) - 2 u1 h1 th1
            {
                float hv = 0.f;
                #pragma unroll
                for (int nt = 0; nt < 8; nt++) {
                    f32x4 wrv = *(const f32x4*)(wr + nt * 16 + fb);
                    #pragma unroll
                    for (int q = 0; q < 4; q++) {
                        float h   = unpB(h1B, nt, q);
                        float th1 = unpB(t1B, nt, q);
                        float u1  = unpB(u1B, nt, q);
                        float td1 = acc[nt][q] * (1.f - h * h) - 2.f * u1 * h * th1;
                        hv = fmaf(td1, wrv[q], hv);
                    }
                }
                hv += __shfl_xor(hv, 16, 64);
                hv += __shfl_xor(hv, 32, 64);
                if (lane < 16) out[(long)(4 + dir) * N + sbase + lane] = hv;
            }
        }
    }
}

extern "C" void kernel_launch(void* const* d_in, const int* in_sizes, int n_in,
                              void* d_out, int out_size, void* d_ws, size_t ws_size,
                              hipStream_t stream) {
    const float* X  = (const float*)d_in[0];
    const float* W1 = (const float*)d_in[1];
    const float* B1 = (const float*)d_in[2];
    const float* W2 = (const float*)d_in[3];
    const float* B2 = (const float*)d_in[4];
    const float* W3 = (const float*)d_in[5];
    const float* B3 = (const float*)d_in[6];
    const float* W4 = (const float*)d_in[7];
    const float* B4 = (const float*)d_in[8];
    float* out = (float*)d_out;
    const int N = in_sizes[0] / 3;

    mlp_mfma_kernel<<<NBLK, TPB, 0, stream>>>(X, W1, B1, W2, B2, W3, B3, W4, B4, out, N);
}

// Round 5
// 2042.815 us; speedup vs baseline: 1.1227x; 1.1227x over previous
//
#include <hip/hip_runtime.h>
#include <hip/hip_bf16.h>

#define TPB  512
#define NBLK 256

typedef short    short8 __attribute__((ext_vector_type(8)));
typedef float    f32x4  __attribute__((ext_vector_type(4)));
typedef unsigned uint4v __attribute__((ext_vector_type(4)));

#define PROW 136            // panel row stride in shorts (272B = odd*16B)
#define PSZ  (128 * PROW)   // shorts per panel

__device__ __forceinline__ float fast_tanh(float z) {
    float e = __expf(2.0f * z);
    return 1.0f - 2.0f * __builtin_amdgcn_rcpf(e + 1.0f);
}

__device__ __forceinline__ unsigned short bf16_bits(float v) {
    __hip_bfloat16 b = __float2bfloat16(v);
    unsigned short s; __builtin_memcpy(&s, &b, 2);
    return s;
}

__device__ __forceinline__ unsigned pack_bf2(float lo, float hi) {
    return (unsigned)bf16_bits(lo) | ((unsigned)bf16_bits(hi) << 16);
}

// B-frag kk = bf16 pack of acc rows (nt=kk, nt=kk+4)  [sigma k-permutation]
__device__ __forceinline__ short8 packB(f32x4 lo, f32x4 hi) {
    uint4v u;
    u[0] = pack_bf2(lo[0], lo[1]);
    u[1] = pack_bf2(lo[2], lo[3]);
    u[2] = pack_bf2(hi[0], hi[1]);
    u[3] = pack_bf2(hi[2], hi[3]);
    return __builtin_bit_cast(short8, u);
}

// read back acc-position (nt,q) from packed B-frags (nt,q compile-time)
__device__ __forceinline__ float unpB(const short8* B, int nt, int q) {
    unsigned short us = B[nt & 3][((nt >> 2) << 2) | q];
    return __builtin_bit_cast(float, ((unsigned)us) << 16);
}

// One GEMM D[n][s] += A(panel)*B, single B-stream, acc 8x f32x4 (32 VGPR).
__device__ __forceinline__ void gemm1(const unsigned short* __restrict__ pnl,
                                      int c, int g, const short8 B[4], f32x4 acc[8]) {
    #pragma unroll
    for (int kk = 0; kk < 4; kk++) {
        #pragma unroll
        for (int nt = 0; nt < 8; nt++) {
            const short8 af = *reinterpret_cast<const short8*>(
                pnl + (nt * 16 + c) * PROW + kk * 32 + g * 8);
            acc[nt] = __builtin_amdgcn_mfma_f32_16x16x32_bf16(af, B[kk], acc[nt], 0, 0, 0);
        }
    }
}

__device__ __forceinline__ void zero_acc(f32x4 acc[8]) {
    #pragma unroll
    for (int nt = 0; nt < 8; nt++) acc[nt] = f32x4{0.f, 0.f, 0.f, 0.f};
}

// launch_bounds 2nd arg is CUDA-style min-BLOCKS/CU on this toolchain
// (rounds 2-4: arg=2 pinned VGPR_Count=128 -> catastrophic spill).
// 1 block/CU (LDS-forced anyway) -> 256-reg budget.
__global__ __launch_bounds__(TPB, 1) __attribute__((amdgpu_waves_per_eu(2, 2)))
void mlp_mfma_kernel(
    const float* __restrict__ X,
    const float* __restrict__ gW1, const float* __restrict__ gB1,
    const float* __restrict__ gW2, const float* __restrict__ gB2,
    const float* __restrict__ gW3, const float* __restrict__ gB3,
    const float* __restrict__ gW4, const float* __restrict__ gB4,
    float* __restrict__ out, int N)
{
    // 4 weight panels as MFMA A-operands: [n][sigma(k)], row stride 136 shorts.
    // 0: W2 fwd (W2[f][n])  1: W2 bwd (W2[n][f])  2: W3 fwd  3: W3 bwd
    __shared__ alignas(16) unsigned short sPanel[4 * PSZ];      // 139264 B
    __shared__ alignas(16) float sParam[7 * 128];               // w1t w1x w1y b1 b2 b3 w4

    const int tid = threadIdx.x;
    for (int idx = tid; idx < 4 * 128 * 128; idx += TPB) {
        int p = idx >> 14, e = idx & 16383, n = e >> 7, pp = e & 127;
        int kk = pp >> 5, gg = (pp >> 3) & 3, jj = pp & 7;
        int f = ((((jj >> 2) << 2) | kk) << 4) | (gg << 2) | (jj & 3);  // invsigma
        const float* Wsrc = (p < 2) ? gW2 : gW3;
        float v = (p & 1) ? Wsrc[n * 128 + f] : Wsrc[f * 128 + n];
        sPanel[p * PSZ + n * PROW + pp] = bf16_bits(v);
    }
    if (tid < 128) {
        sParam[0 * 128 + tid] = gW1[tid];
        sParam[1 * 128 + tid] = gW1[128 + tid];
        sParam[2 * 128 + tid] = gW1[256 + tid];
        sParam[3 * 128 + tid] = gB1[tid];
        sParam[4 * 128 + tid] = gB2[tid];
        sParam[5 * 128 + tid] = gB3[tid];
        sParam[6 * 128 + tid] = gW4[tid];
    }
    __syncthreads();

    const int lane = tid & 63;
    const int wave = tid >> 6;
    const int c = lane & 15, g = lane >> 4;
    const int fb = g << 2;   // lane's feature offset within each 16-row tile
    const unsigned short* const pW2f = sPanel;
    const unsigned short* const pW2b = sPanel + PSZ;
    const unsigned short* const pW3f = sPanel + 2 * PSZ;
    const unsigned short* const pW3b = sPanel + 3 * PSZ;
    const float b4 = gB4[0];

    const int tiles = N >> 4;
    for (int t = blockIdx.x * 8 + wave; t < tiles; t += NBLK * 8) {
        const int sbase = t << 4;
        const float* xp = X + (long)(sbase + c) * 3;
        const float xt = xp[0], xx = xp[1], xy = xp[2];

        // ---- Phase A: h1 = tanh(x @ W1 + b1), packed only ----
        short8 h1B[4];
        #pragma unroll
        for (int kk = 0; kk < 4; kk++) {
            f32x4 lo, hi;
            #pragma unroll
            for (int half = 0; half < 2; half++) {
                const int nt = kk + half * 4, f0 = nt * 16 + fb;
                f32x4 wt = *(const f32x4*)(sParam + 0 * 128 + f0);
                f32x4 wx = *(const f32x4*)(sParam + 1 * 128 + f0);
                f32x4 wy = *(const f32x4*)(sParam + 2 * 128 + f0);
                f32x4 bb = *(const f32x4*)(sParam + 3 * 128 + f0);
                f32x4 r;
                #pragma unroll
                for (int q = 0; q < 4; q++)
                    r[q] = fast_tanh(fmaf(xt, wt[q], fmaf(xx, wx[q], fmaf(xy, wy[q], bb[q]))));
                if (half) hi = r; else lo = r;
            }
            h1B[kk] = packB(lo, hi);
        }

        f32x4 acc[8];
        // ---- z2 = W2^T h1 + b2 ----
        #pragma unroll
        for (int nt = 0; nt < 8; nt++)
            acc[nt] = *(const f32x4*)(sParam + 4 * 128 + nt * 16 + fb);
        gemm1(pW2f, c, g, h1B, acc);

        // ---- h2 ----
        short8 h2B[4];
        #pragma unroll
        for (int kk = 0; kk < 4; kk++) {
            f32x4 lo, hi;
            #pragma unroll
            for (int q = 0; q < 4; q++) {
                lo[q] = fast_tanh(acc[kk][q]);
                hi[q] = fast_tanh(acc[kk + 4][q]);
            }
            h2B[kk] = packB(lo, hi);
        }

        // ---- z3 = W3^T h2 + b3 ----
        #pragma unroll
        for (int nt = 0; nt < 8; nt++)
            acc[nt] = *(const f32x4*)(sParam + 5 * 128 + nt * 16 + fb);
        gemm1(pW3f, c, g, h2B, acc);

        // ---- h3, value out, d3 = w4*(1-h3^2), s3 = -2*w4*h3*(1-h3^2) ----
        short8 d3B[4], s3B[4];
        {
            float cp = 0.f;
            #pragma unroll
            for (int kk = 0; kk < 4; kk++) {
                f32x4 dlo, dhi, slo, shi;
                #pragma unroll
                for (int half = 0; half < 2; half++) {
                    const int nt = kk + half * 4;
                    f32x4 w4v = *(const f32x4*)(sParam + 6 * 128 + nt * 16 + fb);
                    #pragma unroll
                    for (int q = 0; q < 4; q++) {
                        float h = fast_tanh(acc[nt][q]);
                        float a = 1.f - h * h;
                        cp = fmaf(h, w4v[q], cp);
                        float d = w4v[q] * a;
                        float s = -2.f * h * d;
                        if (half) { dhi[q] = d; shi[q] = s; }
                        else      { dlo[q] = d; slo[q] = s; }
                    }
                }
                d3B[kk] = packB(dlo, dhi);
                s3B[kk] = packB(slo, shi);
            }
            cp += __shfl_xor(cp, 16, 64);
            cp += __shfl_xor(cp, 32, 64);
            if (lane < 16) out[sbase + lane] = cp + b4;
        }

        // ---- u2 = W3 d3 ----
        zero_acc(acc);
        gemm1(pW3b, c, g, d3B, acc);
        short8 u2B[4], d2B[4];
        #pragma unroll
        for (int kk = 0; kk < 4; kk++) {
            u2B[kk] = packB(acc[kk], acc[kk + 4]);
            f32x4 lo, hi;
            #pragma unroll
            for (int q = 0; q < 4; q++) {
                float h2l = unpB(h2B, kk, q),     h2h = unpB(h2B, kk + 4, q);
                lo[q] = acc[kk][q]     * (1.f - h2l * h2l);
                hi[q] = acc[kk + 4][q] * (1.f - h2h * h2h);
            }
            d2B[kk] = packB(lo, hi);
        }

        // ---- u1 = W2 d2 ----
        zero_acc(acc);
        gemm1(pW2b, c, g, d2B, acc);

        // ---- gradients (u1 still f32 in acc) + save u1B ----
        short8 u1B[4];
        {
            float gt = 0.f, gx = 0.f, gy = 0.f;
            #pragma unroll
            for (int nt = 0; nt < 8; nt++) {
                const int f0 = nt * 16 + fb;
                f32x4 wt = *(const f32x4*)(sParam + 0 * 128 + f0);
                f32x4 wx = *(const f32x4*)(sParam + 1 * 128 + f0);
                f32x4 wy = *(const f32x4*)(sParam + 2 * 128 + f0);
                #pragma unroll
                for (int q = 0; q < 4; q++) {
                    float h = unpB(h1B, nt, q);
                    float d1 = acc[nt][q] * (1.f - h * h);
                    gt = fmaf(d1, wt[q], gt);
                    gx = fmaf(d1, wx[q], gx);
                    gy = fmaf(d1, wy[q], gy);
                }
            }
            gt += __shfl_xor(gt, 16, 64); gt += __shfl_xor(gt, 32, 64);
            gx += __shfl_xor(gx, 16, 64); gx += __shfl_xor(gx, 32, 64);
            gy += __shfl_xor(gy, 16, 64); gy += __shfl_xor(gy, 32, 64);
            if (lane < 16) {
                long s = sbase + lane;
                out[(long)N + s] = gt;
                out[2L * N + s]  = gx;
                out[3L * N + s]  = gy;
            }
            #pragma unroll
            for (int kk = 0; kk < 4; kk++) u1B[kk] = packB(acc[kk], acc[kk + 4]);
        }

        // ---- HVP passes (dir 0: e_x -> W1 row 1; dir 1: e_y -> W1 row 2) ----
        for (int dir = 0; dir < 2; dir++) {
            const float* wr = sParam + (dir ? 2 : 1) * 128;

            // th1 = (1 - h1^2) * w1r   (operand only; recomputed later, not saved)
            {
                short8 t1B[4];
                #pragma unroll
                for (int kk = 0; kk < 4; kk++) {
                    f32x4 lo, hi;
                    #pragma unroll
                    for (int half = 0; half < 2; half++) {
                        const int nt = kk + half * 4;
                        f32x4 wrv = *(const f32x4*)(wr + nt * 16 + fb);
                        f32x4 r;
                        #pragma unroll
                        for (int q = 0; q < 4; q++) {
                            float h = unpB(h1B, nt, q);
                            r[q] = (1.f - h * h) * wrv[q];
                        }
                        if (half) hi = r; else lo = r;
                    }
                    t1B[kk] = packB(lo, hi);
                }
                zero_acc(acc);
                gemm1(pW2f, c, g, t1B, acc);     // tz2
            }

            // th2 = (1 - h2^2) * tz2
            short8 t2B[4];
            #pragma unroll
            for (int kk = 0; kk < 4; kk++) {
                f32x4 lo, hi;
                #pragma unroll
                for (int q = 0; q < 4; q++) {
                    float h2l = unpB(h2B, kk, q),     h2h = unpB(h2B, kk + 4, q);
                    lo[q] = (1.f - h2l * h2l) * acc[kk][q];
                    hi[q] = (1.f - h2h * h2h) * acc[kk + 4][q];
                }
                t2B[kk] = packB(lo, hi);
            }

            zero_acc(acc);
            gemm1(pW3f, c, g, t2B, acc);     // tz3

            // td3 = s3 * tz3
            {
                short8 td3B[4];
                #pragma unroll
                for (int kk = 0; kk < 4; kk++) {
                    f32x4 lo, hi;
                    #pragma unroll
                    for (int q = 0; q < 4; q++) {
                        lo[q] = unpB(s3B, kk, q)     * acc[kk][q];
                        hi[q] = unpB(s3B, kk + 4, q) * acc[kk + 4][q];
                    }
                    td3B[kk] = packB(lo, hi);
                }
                zero_acc(acc);
                gemm1(pW3b, c, g, td3B, acc);    // tu2
            }

            // td2 = tu2*(1-h2^2) - 2 u2 h2 th2
            {
                short8 td2B[4];
                #pragma unroll
                for (int kk = 0; kk < 4; kk++) {
                    f32x4 lo, hi;
                    #pragma unroll
                    for (int half = 0; half < 2; half++) {
                        const int nt = kk + half * 4;
                        f32x4 r;
                        #pragma unroll
                        for (int q = 0; q < 4; q++) {
                            float h   = unpB(h2B, nt, q);
                            float th2 = unpB(t2B, nt, q);
                            float u2  = unpB(u2B, nt, q);
                            r[q] = acc[nt][q] * (1.f - h * h) - 2.f * u2 * h * th2;
                        }
                        if (half) hi = r; else lo = r;
                    }
                    td2B[kk] = packB(lo, hi);
                }
                zero_acc(acc);
                gemm1(pW2b, c, g, td2B, acc);    // tu1
            }

            // hv = sum td1 * w1r,  td1 = tu1*(1-h1^2) - 2 u1 h1 (1-h1^2) w1r
            {
                float hv = 0.f;
                #pragma unroll
                for (int nt = 0; nt < 8; nt++) {
                    f32x4 wrv = *(const f32x4*)(wr + nt * 16 + fb);
                    #pragma unroll
                    for (int q = 0; q < 4; q++) {
                        float h   = unpB(h1B, nt, q);
                        float a   = 1.f - h * h;
                        float u1  = unpB(u1B, nt, q);
                        float td1 = acc[nt][q] * a - 2.f * u1 * h * (a * wrv[q]);
                        hv = fmaf(td1, wrv[q], hv);
                    }
                }
                hv += __shfl_xor(hv, 16, 64);
                hv += __shfl_xor(hv, 32, 64);
                if (lane < 16) out[(long)(4 + dir) * N + sbase + lane] = hv;
            }
        }
    }
}

extern "C" void kernel_launch(void* const* d_in, const int* in_sizes, int n_in,
                              void* d_out, int out_size, void* d_ws, size_t ws_size,
                              hipStream_t stream) {
    const float* X  = (const float*)d_in[0];
    const float* W1 = (const float*)d_in[1];
    const float* B1 = (const float*)d_in[2];
    const float* W2 = (const float*)d_in[3];
    const float* B2 = (const float*)d_in[4];
    const float* W3 = (const float*)d_in[5];
    const float* B3 = (const float*)d_in[6];
    const float* W4 = (const float*)d_in[7];
    const float* B4 = (const float*)d_in[8];
    float* out = (float*)d_out;
    const int N = in_sizes[0] / 3;

    mlp_mfma_kernel<<<NBLK, TPB, 0, stream>>>(X, W1, B1, W2, B2, W3, B3, W4, B4, out, N);
}

// Round 6
// 1424.189 us; speedup vs baseline: 1.6104x; 1.4344x over previous
//
#include <hip/hip_runtime.h>
#include <hip/hip_bf16.h>

#define TPB  512
#define NBLK 256

typedef short    short8 __attribute__((ext_vector_type(8)));
typedef float    f32x4  __attribute__((ext_vector_type(4)));
typedef unsigned uint4v __attribute__((ext_vector_type(4)));

#define PROW 136            // panel row stride in shorts (272B = odd*16B)
#define PSZ  (128 * PROW)   // shorts per panel

__device__ __forceinline__ float fast_tanh(float z) {
    float e = __expf(2.0f * z);
    return 1.0f - 2.0f * __builtin_amdgcn_rcpf(e + 1.0f);
}

__device__ __forceinline__ unsigned short bf16_bits(float v) {
    __hip_bfloat16 b = __float2bfloat16(v);
    unsigned short s; __builtin_memcpy(&s, &b, 2);
    return s;
}

__device__ __forceinline__ unsigned pack_bf2(float lo, float hi) {
    return (unsigned)bf16_bits(lo) | ((unsigned)bf16_bits(hi) << 16);
}

// B-frag kk = bf16 pack of acc rows (nt=kk, nt=kk+4)  [sigma k-permutation]
__device__ __forceinline__ short8 packB(f32x4 lo, f32x4 hi) {
    uint4v u;
    u[0] = pack_bf2(lo[0], lo[1]);
    u[1] = pack_bf2(lo[2], lo[3]);
    u[2] = pack_bf2(hi[0], hi[1]);
    u[3] = pack_bf2(hi[2], hi[3]);
    return __builtin_bit_cast(short8, u);
}

// read back acc-position (nt,q) from packed B-frags (nt,q compile-time)
__device__ __forceinline__ float unpB(const short8* B, int nt, int q) {
    unsigned short us = B[nt & 3][((nt >> 2) << 2) | q];
    return __builtin_bit_cast(float, ((unsigned)us) << 16);
}

// One GEMM D[n][s] += A(panel)*B, single B-stream, acc 8x f32x4 (32 VGPR).
__device__ __forceinline__ void gemm1(const unsigned short* __restrict__ pnl,
                                      int c, int g, const short8 B[4], f32x4 acc[8]) {
    #pragma unroll
    for (int kk = 0; kk < 4; kk++) {
        #pragma unroll
        for (int nt = 0; nt < 8; nt++) {
            const short8 af = *reinterpret_cast<const short8*>(
                pnl + (nt * 16 + c) * PROW + kk * 32 + g * 8);
            acc[nt] = __builtin_amdgcn_mfma_f32_16x16x32_bf16(af, B[kk], acc[nt], 0, 0, 0);
        }
    }
}

__device__ __forceinline__ void zero_acc(f32x4 acc[8]) {
    #pragma unroll
    for (int nt = 0; nt < 8; nt++) acc[nt] = f32x4{0.f, 0.f, 0.f, 0.f};
}

__device__ __forceinline__ float red16(float v) {
    v += __shfl_xor(v, 16, 64);
    v += __shfl_xor(v, 32, 64);
    return v;
}

// layer-1 jets for direction wd: vB=h1, tB=(1-h1^2)*wd, sB=-h1(1-h1^2)*wd^2
// vB/sB may be null (compile-time) to skip.
__device__ __forceinline__ void layer1_jets(const float* sP, int fb,
                                            float xt, float xx, float xy,
                                            const float* wd,
                                            short8* vB, short8* tB, short8* sB) {
    #pragma unroll
    for (int kk = 0; kk < 4; kk++) {
        f32x4 vlo, vhi, tlo, thi, slo, shi;
        #pragma unroll
        for (int half = 0; half < 2; half++) {
            const int nt = kk + half * 4, f0 = nt * 16 + fb;
            f32x4 wt = *(const f32x4*)(sP + 0 * 128 + f0);
            f32x4 wx = *(const f32x4*)(sP + 1 * 128 + f0);
            f32x4 wy = *(const f32x4*)(sP + 2 * 128 + f0);
            f32x4 bb = *(const f32x4*)(sP + 3 * 128 + f0);
            f32x4 wdv = *(const f32x4*)(wd + f0);
            f32x4 v, t, s;
            #pragma unroll
            for (int q = 0; q < 4; q++) {
                float z = fmaf(xt, wt[q], fmaf(xx, wx[q], fmaf(xy, wy[q], bb[q])));
                float h = fast_tanh(z);
                float a = 1.f - h * h;
                v[q] = h;
                t[q] = a * wdv[q];
                s[q] = -h * a * wdv[q] * wdv[q];
            }
            if (half) { vhi = v; thi = t; shi = s; }
            else      { vlo = v; tlo = t; slo = s; }
        }
        if (vB) vB[kk] = packB(vlo, vhi);
        tB[kk] = packB(tlo, thi);
        if (sB) sB[kk] = packB(slo, shi);
    }
}

__device__ __forceinline__ void jet_save(unsigned short* slot, int lane, const short8 B[4]) {
    #pragma unroll
    for (int kk = 0; kk < 4; kk++)
        *reinterpret_cast<short8*>(slot + ((kk << 6) + lane) * 8) = B[kk];
}
__device__ __forceinline__ void jet_load(const unsigned short* slot, int lane, short8 B[4]) {
    #pragma unroll
    for (int kk = 0; kk < 4; kk++)
        B[kk] = *reinterpret_cast<const short8*>(slot + ((kk << 6) + lane) * 8);
}

__global__ __launch_bounds__(TPB)
void mlp_jet_kernel(
    const float* __restrict__ X,
    const float* __restrict__ gW1, const float* __restrict__ gB1,
    const float* __restrict__ gW2, const float* __restrict__ gB2,
    const float* __restrict__ gW3, const float* __restrict__ gB3,
    const float* __restrict__ gW4, const float* __restrict__ gB4,
    float* __restrict__ out, int N)
{
    // forward-only weight panels as MFMA A-operands: panel[n][sigma(f)] = W[f][n]
    __shared__ alignas(16) unsigned short sPanel[2 * PSZ];       // 69632 B
    __shared__ alignas(16) float sParam[7 * 128];                // 3584 B
    __shared__ alignas(16) unsigned short sJet[8 * 2 * 2048];    // 65536 B (h2,h3 per wave)

    const int tid = threadIdx.x;
    for (int idx = tid; idx < 2 * 128 * 128; idx += TPB) {
        int p = idx >> 14, e = idx & 16383, n = e >> 7, pp = e & 127;
        int kk = pp >> 5, gg = (pp >> 3) & 3, jj = pp & 7;
        int f = ((((jj >> 2) << 2) | kk) << 4) | (gg << 2) | (jj & 3);  // invsigma
        const float* Wsrc = p ? gW3 : gW2;
        sPanel[p * PSZ + n * PROW + pp] = bf16_bits(Wsrc[f * 128 + n]);
    }
    if (tid < 128) {
        sParam[0 * 128 + tid] = gW1[tid];
        sParam[1 * 128 + tid] = gW1[128 + tid];
        sParam[2 * 128 + tid] = gW1[256 + tid];
        sParam[3 * 128 + tid] = gB1[tid];
        sParam[4 * 128 + tid] = gB2[tid];
        sParam[5 * 128 + tid] = gB3[tid];
        sParam[6 * 128 + tid] = gW4[tid];
    }
    __syncthreads();

    const int lane = tid & 63;
    const int wave = tid >> 6;
    const int c = lane & 15, g = lane >> 4;
    const int fb = g << 2;
    const unsigned short* const pW2f = sPanel;
    const unsigned short* const pW3f = sPanel + PSZ;
    unsigned short* const slotH2 = sJet + wave * 2 * 2048;
    unsigned short* const slotH3 = slotH2 + 2048;
    const float b4 = gB4[0];

    const int tiles = N >> 4;
    for (int t = blockIdx.x * 8 + wave; t < tiles; t += NBLK * 8) {
        const int sbase = t << 4;
        const float* xp = X + (long)(sbase + c) * 3;
        const float xt = xp[0], xx = xp[1], xy = xp[2];

        f32x4 acc[8];

        // ================= SP1: value + x-direction jets =================
        {
            short8 vB[4], tB[4], sB[4];
            layer1_jets(sParam, fb, xt, xx, xy, sParam + 1 * 128, vB, tB, sB);

            // z2 = W2^T h1 + b2
            #pragma unroll
            for (int nt = 0; nt < 8; nt++)
                acc[nt] = *(const f32x4*)(sParam + 4 * 128 + nt * 16 + fb);
            gemm1(pW2f, c, g, vB, acc);

            short8 h2B[4];
            #pragma unroll
            for (int kk = 0; kk < 4; kk++) {
                f32x4 lo, hi;
                #pragma unroll
                for (int q = 0; q < 4; q++) {
                    lo[q] = fast_tanh(acc[kk][q]);
                    hi[q] = fast_tanh(acc[kk + 4][q]);
                }
                h2B[kk] = packB(lo, hi);
            }
            jet_save(slotH2, lane, h2B);

            // tz2x
            zero_acc(acc);
            gemm1(pW2f, c, g, tB, acc);
            short8 t2B[4], p2B[4];
            #pragma unroll
            for (int kk = 0; kk < 4; kk++) {
                f32x4 tlo, thi, plo, phi;
                #pragma unroll
                for (int half = 0; half < 2; half++) {
                    const int nt = kk + half * 4;
                    f32x4 tv, pv;
                    #pragma unroll
                    for (int q = 0; q < 4; q++) {
                        float h = unpB(h2B, nt, q);
                        float a = 1.f - h * h;
                        float tz = acc[nt][q];
                        tv[q] = a * tz;
                        pv[q] = -h * a * tz * tz;
                    }
                    if (half) { thi = tv; phi = pv; } else { tlo = tv; plo = pv; }
                }
                t2B[kk] = packB(tlo, thi);
                p2B[kk] = packB(plo, phi);
            }

            // sz2x -> sh2x = a2*sz2x + p2
            zero_acc(acc);
            gemm1(pW2f, c, g, sB, acc);
            short8 s2B[4];
            #pragma unroll
            for (int kk = 0; kk < 4; kk++) {
                f32x4 lo, hi;
                #pragma unroll
                for (int half = 0; half < 2; half++) {
                    const int nt = kk + half * 4;
                    f32x4 sv;
                    #pragma unroll
                    for (int q = 0; q < 4; q++) {
                        float h = unpB(h2B, nt, q);
                        float a = 1.f - h * h;
                        sv[q] = fmaf(a, acc[nt][q], unpB(p2B, nt, q));
                    }
                    if (half) hi = sv; else lo = sv;
                }
                s2B[kk] = packB(lo, hi);
            }

            // z3 = W3^T h2 + b3
            #pragma unroll
            for (int nt = 0; nt < 8; nt++)
                acc[nt] = *(const f32x4*)(sParam + 5 * 128 + nt * 16 + fb);
            gemm1(pW3f, c, g, h2B, acc);

            short8 h3B[4];
            float cp = 0.f;
            #pragma unroll
            for (int kk = 0; kk < 4; kk++) {
                f32x4 lo, hi;
                #pragma unroll
                for (int half = 0; half < 2; half++) {
                    const int nt = kk + half * 4;
                    f32x4 w4v = *(const f32x4*)(sParam + 6 * 128 + nt * 16 + fb);
                    f32x4 hv;
                    #pragma unroll
                    for (int q = 0; q < 4; q++) {
                        float h = fast_tanh(acc[nt][q]);
                        cp = fmaf(h, w4v[q], cp);
                        hv[q] = h;
                    }
                    if (half) hi = hv; else lo = hv;
                }
                h3B[kk] = packB(lo, hi);
            }
            jet_save(slotH3, lane, h3B);
            cp = red16(cp);
            if (lane < 16) out[sbase + lane] = cp + b4;

            // tz3x -> gx, p3 accumulation
            zero_acc(acc);
            gemm1(pW3f, c, g, t2B, acc);
            float c1 = 0.f, p3 = 0.f;
            #pragma unroll
            for (int nt = 0; nt < 8; nt++) {
                f32x4 w4v = *(const f32x4*)(sParam + 6 * 128 + nt * 16 + fb);
                #pragma unroll
                for (int q = 0; q < 4; q++) {
                    float h = unpB(h3B, nt, q);
                    float a = 1.f - h * h;
                    float tz = acc[nt][q];
                    float wa = w4v[q] * a;
                    c1 = fmaf(wa, tz, c1);
                    p3 = fmaf(-wa * h, tz * tz, p3);
                }
            }

            // sz3x -> d2x = 2*(sum w4*a3*sz3x + p3)
            zero_acc(acc);
            gemm1(pW3f, c, g, s2B, acc);
            float c2 = p3;
            #pragma unroll
            for (int nt = 0; nt < 8; nt++) {
                f32x4 w4v = *(const f32x4*)(sParam + 6 * 128 + nt * 16 + fb);
                #pragma unroll
                for (int q = 0; q < 4; q++) {
                    float h = unpB(h3B, nt, q);
                    float a = 1.f - h * h;
                    c2 = fmaf(w4v[q] * a, acc[nt][q], c2);
                }
            }
            c1 = red16(c1);
            c2 = red16(c2);
            if (lane < 16) {
                out[2L * N + sbase + lane] = c1;
                out[4L * N + sbase + lane] = 2.f * c2;
            }
        }

        // ================= SP2: y-direction jets =================
        {
            short8 tB[4], sB[4];
            layer1_jets(sParam, fb, xt, xx, xy, sParam + 2 * 128,
                        (short8*)nullptr, tB, sB);

            short8 h2B[4];
            jet_load(slotH2, lane, h2B);

            zero_acc(acc);
            gemm1(pW2f, c, g, tB, acc);
            short8 t2B[4], p2B[4];
            #pragma unroll
            for (int kk = 0; kk < 4; kk++) {
                f32x4 tlo, thi, plo, phi;
                #pragma unroll
                for (int half = 0; half < 2; half++) {
                    const int nt = kk + half * 4;
                    f32x4 tv, pv;
                    #pragma unroll
                    for (int q = 0; q < 4; q++) {
                        float h = unpB(h2B, nt, q);
                        float a = 1.f - h * h;
                        float tz = acc[nt][q];
                        tv[q] = a * tz;
                        pv[q] = -h * a * tz * tz;
                    }
                    if (half) { thi = tv; phi = pv; } else { tlo = tv; plo = pv; }
                }
                t2B[kk] = packB(tlo, thi);
                p2B[kk] = packB(plo, phi);
            }

            zero_acc(acc);
            gemm1(pW2f, c, g, sB, acc);
            short8 s2B[4];
            #pragma unroll
            for (int kk = 0; kk < 4; kk++) {
                f32x4 lo, hi;
                #pragma unroll
                for (int half = 0; half < 2; half++) {
                    const int nt = kk + half * 4;
                    f32x4 sv;
                    #pragma unroll
                    for (int q = 0; q < 4; q++) {
                        float h = unpB(h2B, nt, q);
                        float a = 1.f - h * h;
                        sv[q] = fmaf(a, acc[nt][q], unpB(p2B, nt, q));
                    }
                    if (half) hi = sv; else lo = sv;
                }
                s2B[kk] = packB(lo, hi);
            }

            short8 h3B[4];
            jet_load(slotH3, lane, h3B);

            zero_acc(acc);
            gemm1(pW3f, c, g, t2B, acc);
            float c1 = 0.f, p3 = 0.f;
            #pragma unroll
            for (int nt = 0; nt < 8; nt++) {
                f32x4 w4v = *(const f32x4*)(sParam + 6 * 128 + nt * 16 + fb);
                #pragma unroll
                for (int q = 0; q < 4; q++) {
                    float h = unpB(h3B, nt, q);
                    float a = 1.f - h * h;
                    float tz = acc[nt][q];
                    float wa = w4v[q] * a;
                    c1 = fmaf(wa, tz, c1);
                    p3 = fmaf(-wa * h, tz * tz, p3);
                }
            }

            zero_acc(acc);
            gemm1(pW3f, c, g, s2B, acc);
            float c2 = p3;
            #pragma unroll
            for (int nt = 0; nt < 8; nt++) {
                f32x4 w4v = *(const f32x4*)(sParam + 6 * 128 + nt * 16 + fb);
                #pragma unroll
                for (int q = 0; q < 4; q++) {
                    float h = unpB(h3B, nt, q);
                    float a = 1.f - h * h;
                    c2 = fmaf(w4v[q] * a, acc[nt][q], c2);
                }
            }
            c1 = red16(c1);
            c2 = red16(c2);
            if (lane < 16) {
                out[3L * N + sbase + lane] = c1;
                out[5L * N + sbase + lane] = 2.f * c2;
            }
        }

        // ================= SP3: t-direction (first order only) =================
        {
            short8 tB[4];
            layer1_jets(sParam, fb, xt, xx, xy, sParam + 0 * 128,
                        (short8*)nullptr, tB, (short8*)nullptr);

            short8 h2B[4];
            jet_load(slotH2, lane, h2B);

            zero_acc(acc);
            gemm1(pW2f, c, g, tB, acc);
            short8 t2B[4];
            #pragma unroll
            for (int kk = 0; kk < 4; kk++) {
                f32x4 lo, hi;
                #pragma unroll
                for (int half = 0; half < 2; half++) {
                    const int nt = kk + half * 4;
                    f32x4 tv;
                    #pragma unroll
                    for (int q = 0; q < 4; q++) {
                        float h = unpB(h2B, nt, q);
                        tv[q] = (1.f - h * h) * acc[nt][q];
                    }
                    if (half) hi = tv; else lo = tv;
                }
                t2B[kk] = packB(lo, hi);
            }

            short8 h3B[4];
            jet_load(slotH3, lane, h3B);

            zero_acc(acc);
            gemm1(pW3f, c, g, t2B, acc);
            float c1 = 0.f;
            #pragma unroll
            for (int nt = 0; nt < 8; nt++) {
                f32x4 w4v = *(const f32x4*)(sParam + 6 * 128 + nt * 16 + fb);
                #pragma unroll
                for (int q = 0; q < 4; q++) {
                    float h = unpB(h3B, nt, q);
                    float a = 1.f - h * h;
                    c1 = fmaf(w4v[q] * a, acc[nt][q], c1);
                }
            }
            c1 = red16(c1);
            if (lane < 16) out[(long)N + sbase + lane] = c1;
        }
    }
}

extern "C" void kernel_launch(void* const* d_in, const int* in_sizes, int n_in,
                              void* d_out, int out_size, void* d_ws, size_t ws_size,
                              hipStream_t stream) {
    const float* X  = (const float*)d_in[0];
    const float* W1 = (const float*)d_in[1];
    const float* B1 = (const float*)d_in[2];
    const float* W2 = (const float*)d_in[3];
    const float* B2 = (const float*)d_in[4];
    const float* W3 = (const float*)d_in[5];
    const float* B3 = (const float*)d_in[6];
    const float* W4 = (const float*)d_in[7];
    const float* B4 = (const float*)d_in[8];
    float* out = (float*)d_out;
    const int N = in_sizes[0] / 3;

    mlp_jet_kernel<<<NBLK, TPB, 0, stream>>>(X, W1, B1, W2, B2, W3, B3, W4, B4, out, N);
}

// Round 7
// 1249.199 us; speedup vs baseline: 1.8359x; 1.1401x over previous
//
#include <hip/hip_runtime.h>
#include <hip/hip_bf16.h>

#define TPB  512
#define NBLK 256
#define PROW 136            // panel row stride in shorts (272B = odd*16B)
#define PSZ  (128 * PROW)   // shorts per panel

typedef short    short8 __attribute__((ext_vector_type(8)));
typedef float    f32x4  __attribute__((ext_vector_type(4)));
typedef unsigned uint4v __attribute__((ext_vector_type(4)));

// NO local arrays anywhere: named-member structs by value only (SROA-proof).
struct Frag  { short8 k0, k1, k2, k3; };
struct Frag2 { Frag t, p; };
struct Acc8  { f32x4 n0, n1, n2, n3, n4, n5, n6, n7; };
struct HTS   { f32x4 h, t, s; };
struct F2    { float a, b; };

__device__ __forceinline__ f32x4 sp4(float v) { f32x4 r = {v, v, v, v}; return r; }

__device__ __forceinline__ float fast_tanh(float z) {
    float e = __expf(2.0f * z);
    return 1.0f - 2.0f * __builtin_amdgcn_rcpf(e + 1.0f);
}
__device__ __forceinline__ f32x4 tanh4(f32x4 z) {
    f32x4 r;
    r[0] = fast_tanh(z[0]); r[1] = fast_tanh(z[1]);
    r[2] = fast_tanh(z[2]); r[3] = fast_tanh(z[3]);
    return r;
}

__device__ __forceinline__ unsigned short bf16_bits(float v) {
    __hip_bfloat16 b = __float2bfloat16(v);
    unsigned short s; __builtin_memcpy(&s, &b, 2);
    return s;
}
__device__ __forceinline__ unsigned pack_bf2(float lo, float hi) {
    return (unsigned)bf16_bits(lo) | ((unsigned)bf16_bits(hi) << 16);
}
__device__ __forceinline__ short8 packB(f32x4 lo, f32x4 hi) {
    uint4v u;
    u[0] = pack_bf2(lo[0], lo[1]);
    u[1] = pack_bf2(lo[2], lo[3]);
    u[2] = pack_bf2(hi[0], hi[1]);
    u[3] = pack_bf2(hi[2], hi[3]);
    return __builtin_bit_cast(short8, u);
}
__device__ __forceinline__ float bfc(short s) {
    return __builtin_bit_cast(float, ((unsigned)(unsigned short)s) << 16);
}
__device__ __forceinline__ f32x4 unplo(short8 v) {
    f32x4 r; r[0] = bfc(v[0]); r[1] = bfc(v[1]); r[2] = bfc(v[2]); r[3] = bfc(v[3]); return r;
}
__device__ __forceinline__ f32x4 unphi(short8 v) {
    f32x4 r; r[0] = bfc(v[4]); r[1] = bfc(v[5]); r[2] = bfc(v[6]); r[3] = bfc(v[7]); return r;
}

__device__ __forceinline__ Acc8 acc_zero() {
    Acc8 A;
    A.n0 = sp4(0.f); A.n1 = sp4(0.f); A.n2 = sp4(0.f); A.n3 = sp4(0.f);
    A.n4 = sp4(0.f); A.n5 = sp4(0.f); A.n6 = sp4(0.f); A.n7 = sp4(0.f);
    return A;
}
__device__ __forceinline__ Acc8 acc_bias(const float* bp, int fb) {
    Acc8 A;
    A.n0 = *(const f32x4*)(bp + 0 * 16 + fb);
    A.n1 = *(const f32x4*)(bp + 1 * 16 + fb);
    A.n2 = *(const f32x4*)(bp + 2 * 16 + fb);
    A.n3 = *(const f32x4*)(bp + 3 * 16 + fb);
    A.n4 = *(const f32x4*)(bp + 4 * 16 + fb);
    A.n5 = *(const f32x4*)(bp + 5 * 16 + fb);
    A.n6 = *(const f32x4*)(bp + 6 * 16 + fb);
    A.n7 = *(const f32x4*)(bp + 7 * 16 + fb);
    return A;
}

// 16 GEMM tiles D[n][s] += W(panel) * B — 32 explicit MFMAs, literal offsets.
__device__ __forceinline__ Acc8 gemm_frag(const unsigned short* __restrict__ pnl,
                                          int c, int g, Frag B, Acc8 A) {
#define ROW(NT, ACC, KK, BV) { \
    const short8 af = *reinterpret_cast<const short8*>( \
        pnl + ((NT) * 16 + c) * PROW + (KK) * 32 + g * 8); \
    ACC = __builtin_amdgcn_mfma_f32_16x16x32_bf16(af, BV, ACC, 0, 0, 0); }
#define KSTEP(KK, BV) \
    ROW(0, A.n0, KK, BV) ROW(1, A.n1, KK, BV) ROW(2, A.n2, KK, BV) ROW(3, A.n3, KK, BV) \
    ROW(4, A.n4, KK, BV) ROW(5, A.n5, KK, BV) ROW(6, A.n6, KK, BV) ROW(7, A.n7, KK, BV)
    KSTEP(0, B.k0) KSTEP(1, B.k1) KSTEP(2, B.k2) KSTEP(3, B.k3)
#undef KSTEP
#undef ROW
    return A;
}

__device__ __forceinline__ float red16(float v) {
    v += __shfl_xor(v, 16, 64);
    v += __shfl_xor(v, 32, 64);
    return v;
}

// layer-1 jet at feature block f0 for direction weights wd
__device__ __forceinline__ HTS l1jet(const float* sP, int f0, const float* wd,
                                     float xt, float xx, float xy) {
    f32x4 wt = *(const f32x4*)(sP + 0 * 128 + f0);
    f32x4 wx = *(const f32x4*)(sP + 1 * 128 + f0);
    f32x4 wy = *(const f32x4*)(sP + 2 * 128 + f0);
    f32x4 bb = *(const f32x4*)(sP + 3 * 128 + f0);
    f32x4 wdv = *(const f32x4*)(wd + f0);
    f32x4 z = sp4(xt) * wt + sp4(xx) * wx + sp4(xy) * wy + bb;
    f32x4 h = tanh4(z);
    f32x4 a = sp4(1.f) - h * h;
    HTS r; r.h = h; r.t = a * wdv; r.s = (sp4(0.f) - h) * a * wdv * wdv;
    return r;
}

__device__ __forceinline__ Frag tanh_frag(Acc8 A) {
    Frag F;
    F.k0 = packB(tanh4(A.n0), tanh4(A.n4));
    F.k1 = packB(tanh4(A.n1), tanh4(A.n5));
    F.k2 = packB(tanh4(A.n2), tanh4(A.n6));
    F.k3 = packB(tanh4(A.n3), tanh4(A.n7));
    return F;
}

// t = a*tz ; p = -h*a*tz^2
__device__ __forceinline__ Frag2 tjet(Frag h, Acc8 T) {
    Frag2 R;
#define TP(K, NL, NH) { \
    f32x4 hl = unplo(h.K), hh = unphi(h.K); \
    f32x4 al = sp4(1.f) - hl * hl, ah = sp4(1.f) - hh * hh; \
    R.t.K = packB(al * T.NL, ah * T.NH); \
    R.p.K = packB(sp4(0.f) - hl * al * T.NL * T.NL, sp4(0.f) - hh * ah * T.NH * T.NH); }
    TP(k0, n0, n4) TP(k1, n1, n5) TP(k2, n2, n6) TP(k3, n3, n7)
#undef TP
    return R;
}

// s = a*sz + p
__device__ __forceinline__ Frag sjet(Frag h, Acc8 S, Frag p) {
    Frag R;
#define SJ(K, NL, NH) { \
    f32x4 hl = unplo(h.K), hh = unphi(h.K); \
    f32x4 al = sp4(1.f) - hl * hl, ah = sp4(1.f) - hh * hh; \
    R.K = packB(al * S.NL + unplo(p.K), ah * S.NH + unphi(p.K)); }
    SJ(k0, n0, n4) SJ(k1, n1, n5) SJ(k2, n2, n6) SJ(k3, n3, n7)
#undef SJ
    return R;
}

// h3 = tanh(acc), cp = sum w4*h3
__device__ __forceinline__ Frag tanh_dotw4(const float* w4p, int fb, Acc8 A, float& cp) {
    Frag F; f32x4 s = sp4(0.f);
#define TD(K, NL, NH, IL, IH) { \
    f32x4 hl = tanh4(A.NL), hh = tanh4(A.NH); \
    f32x4 wl = *(const f32x4*)(w4p + (IL) * 16 + fb); \
    f32x4 wh = *(const f32x4*)(w4p + (IH) * 16 + fb); \
    s += wl * hl + wh * hh; \
    F.K = packB(hl, hh); }
    TD(k0, n0, n4, 0, 4) TD(k1, n1, n5, 1, 5) TD(k2, n2, n6, 2, 6) TD(k3, n3, n7, 3, 7)
#undef TD
    cp = s[0] + s[1] + s[2] + s[3];
    return F;
}

// a = sum w4*a3*T ; b = sum -w4*a3*h3*T^2
__device__ __forceinline__ F2 dot_tz(const float* w4p, int fb, Frag h, Acc8 T) {
    f32x4 s1 = sp4(0.f), s2 = sp4(0.f);
#define DT(K, NL, NH, IL, IH) { \
    f32x4 wl = *(const f32x4*)(w4p + (IL) * 16 + fb); \
    f32x4 wh = *(const f32x4*)(w4p + (IH) * 16 + fb); \
    f32x4 hl = unplo(h.K), hh = unphi(h.K); \
    f32x4 wal = wl * (sp4(1.f) - hl * hl), wah = wh * (sp4(1.f) - hh * hh); \
    s1 += wal * T.NL + wah * T.NH; \
    s2 -= wal * hl * T.NL * T.NL + wah * hh * T.NH * T.NH; }
    DT(k0, n0, n4, 0, 4) DT(k1, n1, n5, 1, 5) DT(k2, n2, n6, 2, 6) DT(k3, n3, n7, 3, 7)
#undef DT
    F2 r; r.a = s1[0] + s1[1] + s1[2] + s1[3]; r.b = s2[0] + s2[1] + s2[2] + s2[3];
    return r;
}

// sum w4*a3*S
__device__ __forceinline__ float dot_wa(const float* w4p, int fb, Frag h, Acc8 S) {
    f32x4 s = sp4(0.f);
#define DA(K, NL, NH, IL, IH) { \
    f32x4 wl = *(const f32x4*)(w4p + (IL) * 16 + fb); \
    f32x4 wh = *(const f32x4*)(w4p + (IH) * 16 + fb); \
    f32x4 hl = unplo(h.K), hh = unphi(h.K); \
    s += wl * (sp4(1.f) - hl * hl) * S.NL + wh * (sp4(1.f) - hh * hh) * S.NH; }
    DA(k0, n0, n4, 0, 4) DA(k1, n1, n5, 1, 5) DA(k2, n2, n6, 2, 6) DA(k3, n3, n7, 3, 7)
#undef DA
    return s[0] + s[1] + s[2] + s[3];
}

__device__ __forceinline__ void jet_save(unsigned short* slot, int lane, Frag F) {
    short8* p = reinterpret_cast<short8*>(slot);
    p[lane] = F.k0; p[64 + lane] = F.k1; p[128 + lane] = F.k2; p[192 + lane] = F.k3;
}
__device__ __forceinline__ Frag jet_load(const unsigned short* slot, int lane) {
    const short8* p = reinterpret_cast<const short8*>(slot);
    Frag F; F.k0 = p[lane]; F.k1 = p[64 + lane]; F.k2 = p[128 + lane]; F.k3 = p[192 + lane];
    return F;
}

__global__ __launch_bounds__(TPB, 1) __attribute__((amdgpu_waves_per_eu(2)))
void mlp_jet_kernel(
    const float* __restrict__ X,
    const float* __restrict__ gW1, const float* __restrict__ gB1,
    const float* __restrict__ gW2, const float* __restrict__ gB2,
    const float* __restrict__ gW3, const float* __restrict__ gB3,
    const float* __restrict__ gW4, const float* __restrict__ gB4,
    float* __restrict__ out, int N)
{
    __shared__ alignas(16) unsigned short sPanel[2 * PSZ];       // 69632 B
    __shared__ alignas(16) float sParam[7 * 128];                // 3584 B
    __shared__ alignas(16) unsigned short sJet[8 * 2 * 2048];    // 65536 B

    const int tid = threadIdx.x;
    for (int idx = tid; idx < 2 * 128 * 128; idx += TPB) {
        int p = idx >> 14, e = idx & 16383, n = e >> 7, pp = e & 127;
        int kk = pp >> 5, gg = (pp >> 3) & 3, jj = pp & 7;
        int f = ((((jj >> 2) << 2) | kk) << 4) | (gg << 2) | (jj & 3);  // invsigma
        const float* Wsrc = p ? gW3 : gW2;
        sPanel[p * PSZ + n * PROW + pp] = bf16_bits(Wsrc[f * 128 + n]);
    }
    if (tid < 128) {
        sParam[0 * 128 + tid] = gW1[tid];
        sParam[1 * 128 + tid] = gW1[128 + tid];
        sParam[2 * 128 + tid] = gW1[256 + tid];
        sParam[3 * 128 + tid] = gB1[tid];
        sParam[4 * 128 + tid] = gB2[tid];
        sParam[5 * 128 + tid] = gB3[tid];
        sParam[6 * 128 + tid] = gW4[tid];
    }
    __syncthreads();

    const int lane = tid & 63;
    const int wave = tid >> 6;
    const int c = lane & 15, g = lane >> 4;
    const int fb = g << 2;
    const unsigned short* const pW2f = sPanel;
    const unsigned short* const pW3f = sPanel + PSZ;
    unsigned short* const slotH2 = sJet + wave * 4096;
    unsigned short* const slotH3 = slotH2 + 2048;
    const float b4 = gB4[0];
    const float* const w4p = sParam + 6 * 128;

    const int tiles = N >> 4;
    for (int t = blockIdx.x * 8 + wave; t < tiles; t += NBLK * 8) {
        const int sbase = t << 4;
        const float* xp = X + (long)(sbase + c) * 3;
        const float xt = xp[0], xx = xp[1], xy = xp[2];

        // ================= SP1: value + x-direction jets =================
        {
            const float* wd = sParam + 1 * 128;
            Frag vF, tF, sF;
            {
                HTS lo = l1jet(sParam, 0 * 16 + fb, wd, xt, xx, xy);
                HTS hi = l1jet(sParam, 4 * 16 + fb, wd, xt, xx, xy);
                vF.k0 = packB(lo.h, hi.h); tF.k0 = packB(lo.t, hi.t); sF.k0 = packB(lo.s, hi.s);
                lo = l1jet(sParam, 1 * 16 + fb, wd, xt, xx, xy);
                hi = l1jet(sParam, 5 * 16 + fb, wd, xt, xx, xy);
                vF.k1 = packB(lo.h, hi.h); tF.k1 = packB(lo.t, hi.t); sF.k1 = packB(lo.s, hi.s);
                lo = l1jet(sParam, 2 * 16 + fb, wd, xt, xx, xy);
                hi = l1jet(sParam, 6 * 16 + fb, wd, xt, xx, xy);
                vF.k2 = packB(lo.h, hi.h); tF.k2 = packB(lo.t, hi.t); sF.k2 = packB(lo.s, hi.s);
                lo = l1jet(sParam, 3 * 16 + fb, wd, xt, xx, xy);
                hi = l1jet(sParam, 7 * 16 + fb, wd, xt, xx, xy);
                vF.k3 = packB(lo.h, hi.h); tF.k3 = packB(lo.t, hi.t); sF.k3 = packB(lo.s, hi.s);
            }

            Acc8 A = gemm_frag(pW2f, c, g, vF, acc_bias(sParam + 4 * 128, fb));
            Frag h2F = tanh_frag(A);
            jet_save(slotH2, lane, h2F);

            A = gemm_frag(pW2f, c, g, tF, acc_zero());
            Frag2 TP = tjet(h2F, A);
            A = gemm_frag(pW2f, c, g, sF, acc_zero());
            Frag s2F = sjet(h2F, A, TP.p);

            A = gemm_frag(pW3f, c, g, h2F, acc_bias(sParam + 5 * 128, fb));
            float cp;
            Frag h3F = tanh_dotw4(w4p, fb, A, cp);
            jet_save(slotH3, lane, h3F);
            cp = red16(cp);
            if (lane < 16) out[sbase + lane] = cp + b4;

            A = gemm_frag(pW3f, c, g, TP.t, acc_zero());
            F2 r = dot_tz(w4p, fb, h3F, A);
            A = gemm_frag(pW3f, c, g, s2F, acc_zero());
            float c2 = r.b + dot_wa(w4p, fb, h3F, A);
            float c1 = red16(r.a);
            c2 = red16(c2);
            if (lane < 16) {
                out[2L * N + sbase + lane] = c1;
                out[4L * N + sbase + lane] = 2.f * c2;
            }
        }

        // ================= SP2: y-direction jets =================
        {
            const float* wd = sParam + 2 * 128;
            Frag tF, sF;
            {
                HTS lo = l1jet(sParam, 0 * 16 + fb, wd, xt, xx, xy);
                HTS hi = l1jet(sParam, 4 * 16 + fb, wd, xt, xx, xy);
                tF.k0 = packB(lo.t, hi.t); sF.k0 = packB(lo.s, hi.s);
                lo = l1jet(sParam, 1 * 16 + fb, wd, xt, xx, xy);
                hi = l1jet(sParam, 5 * 16 + fb, wd, xt, xx, xy);
                tF.k1 = packB(lo.t, hi.t); sF.k1 = packB(lo.s, hi.s);
                lo = l1jet(sParam, 2 * 16 + fb, wd, xt, xx, xy);
                hi = l1jet(sParam, 6 * 16 + fb, wd, xt, xx, xy);
                tF.k2 = packB(lo.t, hi.t); sF.k2 = packB(lo.s, hi.s);
                lo = l1jet(sParam, 3 * 16 + fb, wd, xt, xx, xy);
                hi = l1jet(sParam, 7 * 16 + fb, wd, xt, xx, xy);
                tF.k3 = packB(lo.t, hi.t); sF.k3 = packB(lo.s, hi.s);
            }

            Frag h2F = jet_load(slotH2, lane);

            Acc8 A = gemm_frag(pW2f, c, g, tF, acc_zero());
            Frag2 TP = tjet(h2F, A);
            A = gemm_frag(pW2f, c, g, sF, acc_zero());
            Frag s2F = sjet(h2F, A, TP.p);

            Frag h3F = jet_load(slotH3, lane);

            A = gemm_frag(pW3f, c, g, TP.t, acc_zero());
            F2 r = dot_tz(w4p, fb, h3F, A);
            A = gemm_frag(pW3f, c, g, s2F, acc_zero());
            float c2 = r.b + dot_wa(w4p, fb, h3F, A);
            float c1 = red16(r.a);
            c2 = red16(c2);
            if (lane < 16) {
                out[3L * N + sbase + lane] = c1;
                out[5L * N + sbase + lane] = 2.f * c2;
            }
        }

        // ================= SP3: t-direction (first order only) =================
        {
            const float* wd = sParam + 0 * 128;
            Frag tF;
            {
                HTS lo = l1jet(sParam, 0 * 16 + fb, wd, xt, xx, xy);
                HTS hi = l1jet(sParam, 4 * 16 + fb, wd, xt, xx, xy);
                tF.k0 = packB(lo.t, hi.t);
                lo = l1jet(sParam, 1 * 16 + fb, wd, xt, xx, xy);
                hi = l1jet(sParam, 5 * 16 + fb, wd, xt, xx, xy);
                tF.k1 = packB(lo.t, hi.t);
                lo = l1jet(sParam, 2 * 16 + fb, wd, xt, xx, xy);
                hi = l1jet(sParam, 6 * 16 + fb, wd, xt, xx, xy);
                tF.k2 = packB(lo.t, hi.t);
                lo = l1jet(sParam, 3 * 16 + fb, wd, xt, xx, xy);
                hi = l1jet(sParam, 7 * 16 + fb, wd, xt, xx, xy);
                tF.k3 = packB(lo.t, hi.t);
            }

            Frag h2F = jet_load(slotH2, lane);

            Acc8 A = gemm_frag(pW2f, c, g, tF, acc_zero());
            Frag2 TP = tjet(h2F, A);

            Frag h3F = jet_load(slotH3, lane);

            A = gemm_frag(pW3f, c, g, TP.t, acc_zero());
            float c1 = red16(dot_wa(w4p, fb, h3F, A));
            if (lane < 16) out[(long)N + sbase + lane] = c1;
        }
    }
}

extern "C" void kernel_launch(void* const* d_in, const int* in_sizes, int n_in,
                              void* d_out, int out_size, void* d_ws, size_t ws_size,
                              hipStream_t stream) {
    const float* X  = (const float*)d_in[0];
    const float* W1 = (const float*)d_in[1];
    const float* B1 = (const float*)d_in[2];
    const float* W2 = (const float*)d_in[3];
    const float* B2 = (const float*)d_in[4];
    const float* W3 = (const float*)d_in[5];
    const float* B3 = (const float*)d_in[6];
    const float* W4 = (const float*)d_in[7];
    const float* B4 = (const float*)d_in[8];
    float* out = (float*)d_out;
    const int N = in_sizes[0] / 3;

    mlp_jet_kernel<<<NBLK, TPB, 0, stream>>>(X, W1, B1, W2, B2, W3, B3, W4, B4, out, N);
}